// Round 2
// baseline (339.852 us; speedup 1.0000x reference)
//
#include <hip/hip_runtime.h>

#define NH 16
#define DH 64
#define DM 1024
#define SEQ 2048
#define BATCH 4
#define NT 16   // K-tiles of 64 in DM

typedef short s16x8 __attribute__((ext_vector_type(8)));
typedef float f32x4 __attribute__((ext_vector_type(4)));

__device__ __forceinline__ unsigned short f2bf(float f) {
  union { float f; unsigned int u; } v; v.f = f;
  unsigned int u = v.u;
  unsigned int r = (u + 0x7fffu + ((u >> 16) & 1u)) >> 16;
  return (unsigned short)r;
}

__device__ __forceinline__ unsigned int pkbf(float a, float b) {
#if __has_builtin(__builtin_amdgcn_cvt_pk_bf16_f32)
  typedef short v2s __attribute__((ext_vector_type(2)));
  v2s r = __builtin_amdgcn_cvt_pk_bf16_f32(a, b);
  union { v2s v; unsigned int u; } cv; cv.v = r;
  return cv.u;
#else
  return (unsigned int)f2bf(a) | ((unsigned int)f2bf(b) << 16);
#endif
}

__device__ __forceinline__ float fexp2(float x) {
#if __has_builtin(__builtin_amdgcn_exp2f)
  return __builtin_amdgcn_exp2f(x);
#else
  return exp2f(x);
#endif
}

__device__ __forceinline__ void gload_lds16(const void* g, void* l) {
  __builtin_amdgcn_global_load_lds(
      (const __attribute__((address_space(1))) unsigned int*)g,
      (__attribute__((address_space(3))) unsigned int*)l, 16, 0, 0);
}

// raw barrier: does NOT drain vmcnt (unlike __syncthreads) + compiler fence
#define GBAR() asm volatile("s_barrier" ::: "memory")
#define LG0()  asm volatile("s_waitcnt lgkmcnt(0)" ::: "memory")

// ---------------- fp32 -> bf16 convert (all tensors in one launch) ----------
__global__ void convert_all(const float* __restrict__ q, const float* __restrict__ kv,
                            const float* __restrict__ w0, const float* __restrict__ w1,
                            const float* __restrict__ w2, const float* __restrict__ w3,
                            unsigned short* __restrict__ oq, unsigned short* __restrict__ okv,
                            unsigned short* __restrict__ ow0, unsigned short* __restrict__ ow1,
                            unsigned short* __restrict__ ow2, unsigned short* __restrict__ ow3) {
  const int NQ4 = (BATCH * SEQ * DM) / 4;
  const int NW4 = (DM * DM) / 4;
  const int total = NQ4 * 2 + NW4 * 4;
  for (int i = blockIdx.x * blockDim.x + threadIdx.x; i < total;
       i += gridDim.x * blockDim.x) {
    const float* s; unsigned short* d; int off;
    if (i < NQ4)            { s = q;  d = oq;  off = i; }
    else if (i < 2 * NQ4)   { s = kv; d = okv; off = i - NQ4; }
    else {
      int j = i - 2 * NQ4; int wsel = j / NW4; off = j - wsel * NW4;
      s = (wsel == 0) ? w0 : (wsel == 1) ? w1 : (wsel == 2) ? w2 : w3;
      d = (wsel == 0) ? ow0 : (wsel == 1) ? ow1 : (wsel == 2) ? ow2 : ow3;
    }
    float4 v = *(const float4*)(s + (size_t)off * 4);
    ushort4 o;
    o.x = f2bf(v.x); o.y = f2bf(v.y); o.z = f2bf(v.z); o.w = f2bf(v.w);
    *(ushort4*)(d + (size_t)off * 4) = o;
  }
}

// ---------------- 256x256 8-phase counted-vmcnt GEMM (m201 template) --------
// 8 waves as 2(M)x4(N); per-wave output 128x64. BK=64. LDS 128KB:
//   buf0: A[256][64] @0, B[256][64] @16384; buf1: A @32768, B @49152 (shorts)
// Chunk-XOR swizzle: row r, 16B-chunk g stored at position g^(r&7)
// (linear gload_lds dest + pre-swizzled global source; swizzled ds_read).
// Staging unit = one 64-row slab = 1 gload_lds_dwordx4 per thread (8KB).
__device__ __forceinline__ void stage_slab(const unsigned short* __restrict__ src,
                                           int row0, int kt,
                                           unsigned short* __restrict__ lds, int tid) {
  const int sr = tid >> 3;                      // 0..63: row within slab
  const int g8 = ((tid & 7) ^ (sr & 7)) * 8;    // pre-swizzled source chunk
  gload_lds16(src + (size_t)(row0 + sr) * DM + kt + g8,
              lds + (tid >> 6) * 512);          // wave-uniform linear dest
}

__device__ __forceinline__ void rd4(const unsigned short* __restrict__ base,
                                    int xg, s16x8 (&f)[4]) {
#pragma unroll
  for (int j = 0; j < 4; ++j)
    f[j] = *(const s16x8*)(base + j * 1024 + xg);
}

template <int H>
__device__ __forceinline__ void mm16(s16x8 (&af)[4], s16x8 (&bf)[4],
                                     f32x4 (*acc)[4]) {
  __builtin_amdgcn_s_setprio(1);
#pragma unroll
  for (int j = 0; j < 4; ++j)
#pragma unroll
    for (int fn = 0; fn < 4; ++fn)
      acc[H * 4 + j][fn] = __builtin_amdgcn_mfma_f32_16x16x32_bf16(
          af[j], bf[fn], acc[H * 4 + j][fn], 0, 0, 0);
  __builtin_amdgcn_s_setprio(0);
}

// Phase plan per iter i (tiles ta=2i->buf0, tb=2i+1->buf1), g1..g8:
//  g1: rd B0(k20)+A0(h0,k20); stage {B-h1,A-h1}(2i+1)->buf1
//  g2: rd A0(h1,k20)                      [bf reused]
//  g3: rd B0(k21)+A0(h0,k21)
//  g4: rd A0(h1,k21); stage {B-h0,A-h0}(2i+2)->buf0; WAIT vmcnt(4)
//  g5: rd B1(k20)+A1(h0,k20); stage {B-h1,A-h1}(2i+2)->buf0
//  g6: rd A1(h1,k20)
//  g7: rd B1(k21)+A1(h0,k21)
//  g8: rd A1(h1,k21); stage {B-h0,A-h0}(2i+3)->buf1; WAIT vmcnt(4)
// each phase then: s_barrier; lgkmcnt(0); setprio(1); 16 MFMA; setprio(0); s_barrier
// Ledger (steady state): after W8(i-1) outstanding=[t1 B0A0 @g8(i-1)]=4;
//  g1 +4 -> 8; at W4: g4-stage +4 -> 12, drain through t1's g1-halves ->
//  vmcnt(4). Symmetric at W8. Youngest drained load always issued 3 phases
//  (~900cy) before its wait -> HBM latency hidden; never drains to 0 mid-loop.
// Liveness: A-h0/B of a tile dead after its P3 (lgkm0-fenced + barrier before
//  the staging phase); A-h1 dead after P4; staged halves never touch live slabs.
__device__ __forceinline__ void gemm8p_tile(const unsigned short* __restrict__ X,
                                            const unsigned short* __restrict__ Wt,
                                            unsigned short* __restrict__ SM,
                                            int m0, int n0, f32x4 (*acc)[4]) {
  const int tid = threadIdx.x;
  const int wv = tid >> 6, lane = tid & 63;
  const int quad = lane >> 4, c = lane & 15;
  const int wr = wv >> 2, wc = wv & 3;          // 2M x 4N wave grid
  const int rA = (wr * 128 + c) * 64;           // shorts
  const int rB = (wc * 64 + c) * 64;
  const int xg0 = (quad ^ (c & 7)) * 8;         // k2=0 chunk offset
  const int xg1 = ((4 + quad) ^ (c & 7)) * 8;   // k2=1
  const int A0 = 0, B0 = 16384, A1 = 32768, B1 = 49152;

  s16x8 af[4], bf[4];

  // ---- prologue: tile0 (4 halves) + tile1 {B-h0,A-h0}; drain tile0
  stage_slab(Wt, n0,       0, SM + B0,         tid);
  stage_slab(Wt, n0 + 64,  0, SM + B0 + 4096,  tid);
  stage_slab(Wt, n0 + 128, 0, SM + B0 + 8192,  tid);
  stage_slab(Wt, n0 + 192, 0, SM + B0 + 12288, tid);
  stage_slab(X,  m0,       0, SM + A0,         tid);
  stage_slab(X,  m0 + 128, 0, SM + A0 + 8192,  tid);
  stage_slab(X,  m0 + 64,  0, SM + A0 + 4096,  tid);
  stage_slab(X,  m0 + 192, 0, SM + A0 + 12288, tid);
  stage_slab(Wt, n0,       64, SM + B1,        tid);
  stage_slab(Wt, n0 + 64,  64, SM + B1 + 4096, tid);
  stage_slab(X,  m0,       64, SM + A1,        tid);
  stage_slab(X,  m0 + 128, 64, SM + A1 + 8192, tid);
  asm volatile("s_waitcnt vmcnt(4)" ::: "memory");
  GBAR();

  for (int i = 0; i < NT / 2; ++i) {
    const int t1k = (2 * i + 1) * 64;
    const int t2 = 2 * i + 2, t3 = 2 * i + 3;
    const int t2k = t2 * 64, t3k = t3 * 64;

    // ---- g1
    rd4(SM + B0 + rB, xg0, bf);
    rd4(SM + A0 + rA, xg0, af);
    stage_slab(Wt, n0 + 128, t1k, SM + B1 + 8192,  tid);
    stage_slab(Wt, n0 + 192, t1k, SM + B1 + 12288, tid);
    stage_slab(X,  m0 + 64,  t1k, SM + A1 + 4096,  tid);
    stage_slab(X,  m0 + 192, t1k, SM + A1 + 12288, tid);
    GBAR(); LG0(); mm16<0>(af, bf, acc); GBAR();

    // ---- g2
    rd4(SM + A0 + rA + 4096, xg0, af);
    GBAR(); LG0(); mm16<1>(af, bf, acc); GBAR();

    // ---- g3
    rd4(SM + B0 + rB, xg1, bf);
    rd4(SM + A0 + rA, xg1, af);
    GBAR(); LG0(); mm16<0>(af, bf, acc); GBAR();

    // ---- g4
    rd4(SM + A0 + rA + 4096, xg1, af);
    if (t2 < NT) {
      stage_slab(Wt, n0,       t2k, SM + B0,        tid);
      stage_slab(Wt, n0 + 64,  t2k, SM + B0 + 4096, tid);
      stage_slab(X,  m0,       t2k, SM + A0,        tid);
      stage_slab(X,  m0 + 128, t2k, SM + A0 + 8192, tid);
      asm volatile("s_waitcnt vmcnt(4)" ::: "memory");
    } else {
      asm volatile("s_waitcnt vmcnt(0)" ::: "memory");
    }
    GBAR(); LG0(); mm16<1>(af, bf, acc); GBAR();

    // ---- g5
    rd4(SM + B1 + rB, xg0, bf);
    rd4(SM + A1 + rA, xg0, af);
    if (t2 < NT) {
      stage_slab(Wt, n0 + 128, t2k, SM + B0 + 8192,  tid);
      stage_slab(Wt, n0 + 192, t2k, SM + B0 + 12288, tid);
      stage_slab(X,  m0 + 64,  t2k, SM + A0 + 4096,  tid);
      stage_slab(X,  m0 + 192, t2k, SM + A0 + 12288, tid);
    }
    GBAR(); LG0(); mm16<0>(af, bf, acc); GBAR();

    // ---- g6
    rd4(SM + A1 + rA + 4096, xg0, af);
    GBAR(); LG0(); mm16<1>(af, bf, acc); GBAR();

    // ---- g7
    rd4(SM + B1 + rB, xg1, bf);
    rd4(SM + A1 + rA, xg1, af);
    GBAR(); LG0(); mm16<0>(af, bf, acc); GBAR();

    // ---- g8
    rd4(SM + A1 + rA + 4096, xg1, af);
    if (t3 < NT) {
      stage_slab(Wt, n0,       t3k, SM + B1,        tid);
      stage_slab(Wt, n0 + 64,  t3k, SM + B1 + 4096, tid);
      stage_slab(X,  m0,       t3k, SM + A1,        tid);
      stage_slab(X,  m0 + 128, t3k, SM + A1 + 8192, tid);
      asm volatile("s_waitcnt vmcnt(4)" ::: "memory");
    } else {
      asm volatile("s_waitcnt vmcnt(0)" ::: "memory");
    }
    GBAR(); LG0(); mm16<1>(af, bf, acc); GBAR();
  }
}

// ---------------- fused QKV projection -------------------------------------
// logical grid (32 m-tiles, 12 n-tiles): y<4 -> Q, y<8 -> K, else V^T.
// XCD-aware bijective swizzle (384 % 8 == 0).
__global__ __launch_bounds__(512, 2)
void gemm_qkv8p(const unsigned short* __restrict__ Xq,
                const unsigned short* __restrict__ Xkv,
                const unsigned short* __restrict__ W0,
                const unsigned short* __restrict__ W1,
                const unsigned short* __restrict__ W2,
                const float* __restrict__ b0, const float* __restrict__ b1,
                const float* __restrict__ b2,
                unsigned short* __restrict__ OQ, unsigned short* __restrict__ OK_,
                unsigned short* __restrict__ OV) {
  __shared__ alignas(16) unsigned short SM[65536];   // 128 KB
  const int wg = blockIdx.y * 32 + blockIdx.x;       // nwg = 384
  const int swz = (wg & 7) * 48 + (wg >> 3);
  const int m0 = (swz & 31) * 256;
  const int yy = swz >> 5;
  const int ysel = yy >> 2;
  const int n0 = (yy & 3) * 256;
  const unsigned short* X = (ysel == 0) ? Xq : Xkv;
  const unsigned short* Wt = (ysel == 0) ? W0 : (ysel == 1) ? W1 : W2;
  const float* bias = (ysel == 0) ? b0 : (ysel == 1) ? b1 : b2;
  unsigned short* Out = (ysel == 0) ? OQ : (ysel == 1) ? OK_ : OV;
  // Q pre-scaled by log2(e)/sqrt(Dh) so attention can use exp2 directly
  const float scale = (ysel == 0) ? 0.1803368801f : 1.0f;

  f32x4 acc[8][4] = {};
  gemm8p_tile(X, Wt, SM, m0, n0, acc);

  const int tid = threadIdx.x;
  const int wv = tid >> 6, lane = tid & 63;
  const int quad = lane >> 4, c = lane & 15;
  const int wr = wv >> 2, wc = wv & 3;
  const int m0w = m0 + wr * 128;
  const int n0w = n0 + wc * 64;
#pragma unroll
  for (int fm = 0; fm < 8; ++fm) {
#pragma unroll
    for (int fn = 0; fn < 4; ++fn) {
      int n = n0w + fn * 16 + c;
      float bv = bias[n];
      int m_base = m0w + fm * 16 + quad * 4;
      if (ysel == 2) {
        // V^T: p -> consecutive s; one 8B store
        int b_ = m_base >> 11, s_ = m_base & 2047, h_ = n >> 6, dh = n & 63;
        size_t idx = (((size_t)(b_ * NH + h_)) * DH + dh) * SEQ + s_;
        ushort4 o4;
        o4.x = f2bf(acc[fm][fn][0] + bv);
        o4.y = f2bf(acc[fm][fn][1] + bv);
        o4.z = f2bf(acc[fm][fn][2] + bv);
        o4.w = f2bf(acc[fm][fn][3] + bv);
        *(ushort4*)(&Out[idx]) = o4;
      } else {
#pragma unroll
        for (int p = 0; p < 4; ++p) {
          int m = m_base + p;
          float val = (acc[fm][fn][p] + bv) * scale;
          int b_ = m >> 11, s_ = m & 2047, h_ = n >> 6, dh = n & 63;
          size_t idx = (((size_t)(b_ * NH + h_)) * SEQ + s_) * DH + dh;
          Out[idx] = f2bf(val);
        }
      }
    }
  }
}

// ---------------- output projection (fp32 out) -----------------------------
__global__ __launch_bounds__(512, 2)
void gemm_o8p(const unsigned short* __restrict__ X,
              const unsigned short* __restrict__ Wt,
              const float* __restrict__ bias, float* __restrict__ Out) {
  __shared__ alignas(16) unsigned short SM[65536];
  const int wg = blockIdx.y * 32 + blockIdx.x;       // nwg = 128
  const int swz = (wg & 7) * 16 + (wg >> 3);
  const int m0 = (swz & 31) * 256;
  const int n0 = (swz >> 5) * 256;
  f32x4 acc[8][4] = {};
  gemm8p_tile(X, Wt, SM, m0, n0, acc);

  const int tid = threadIdx.x;
  const int wv = tid >> 6, lane = tid & 63;
  const int quad = lane >> 4, c = lane & 15;
  const int wr = wv >> 2, wc = wv & 3;
  const int m0w = m0 + wr * 128;
  const int n0w = n0 + wc * 64;
#pragma unroll
  for (int fm = 0; fm < 8; ++fm) {
#pragma unroll
    for (int fn = 0; fn < 4; ++fn) {
      int n = n0w + fn * 16 + c;
      float bv = bias[n];
#pragma unroll
      for (int p = 0; p < 4; ++p) {
        int m = m0w + fm * 16 + quad * 4 + p;
        Out[(size_t)m * DM + n] = acc[fm][fn][p] + bv;
      }
    }
  }
}

// ---------------- flash attention v4 (unchanged this round) ----------------
// S^T = K.Q^T with key-permuted A rows => P^T fragments built IN-REGISTER for
// PV (no LDS P round-trip). Double-buffered K/V staging, ONE barrier per tile.
// Q bf16 pre-scaled by log2(e)/8. Out: attn (b, s, h*64+dh) bf16.
__global__ __launch_bounds__(256, 4)
void attn_kernel(const unsigned short* __restrict__ Qb,
                 const unsigned short* __restrict__ Kb,
                 const unsigned short* __restrict__ VTb,
                 unsigned short* __restrict__ Ob) {
  __shared__ alignas(16) unsigned short SM[16384];   // 32 KB

  const int tid = threadIdx.x, wv_ = tid >> 6, lane = tid & 63;
  const int quad = lane >> 4, c = lane & 15;
  const int bh = blockIdx.x, qb = blockIdx.y;
  const unsigned short* Qp = Qb + (size_t)bh * SEQ * DH;
  const unsigned short* Kp = Kb + (size_t)bh * SEQ * DH;
  const unsigned short* Vp = VTb + (size_t)bh * DH * SEQ;
  const int wq0 = qb * 128 + wv_ * 32;

  // Q fragments (B-operand: lane c = q column) live in registers
  s16x8 aq[2][2];
#pragma unroll
  for (int t = 0; t < 2; ++t)
#pragma unroll
    for (int k2 = 0; k2 < 2; ++k2)
      aq[t][k2] = *(const s16x8*)(Qp + (size_t)(wq0 + t * 16 + c) * DH +
                                  k2 * 32 + quad * 8);

  f32x4 ot[4][2] = {};     // O^T accum: [dh-tile][q-tile], lane c = q col
  float lsum[2] = {};      // per-lane partial row sums (this quad's keys)

  const int srow = lane >> 3;
  const int schunk = (lane & 7) ^ srow;

  // prologue: stage tile 0 -> buffer 0  (K at SM+0/SM+4096, V at +8192/+12288)
#pragma unroll
  for (int i = 0; i < 2; ++i) {
    int reg = wv_ * 2 + i;
    gload_lds16(Kp + (size_t)(reg * 8 + srow) * DH + schunk * 8,
                (void*)(SM + reg * 512));
    gload_lds16(Vp + (size_t)(reg * 8 + srow) * SEQ + schunk * 8,
                (void*)(SM + 8192 + reg * 512));
  }

  for (int kt = 0; kt < SEQ; kt += 64) {
    const int cur = (kt >> 6) & 1;
    __syncthreads();   // drains this tile's loads; frees other buffer
    if (kt + 64 < SEQ) {
      const int nxt = cur ^ 1;
#pragma unroll
      for (int i = 0; i < 2; ++i) {
        int reg = wv_ * 2 + i;
        gload_lds16(Kp + (size_t)(kt + 64 + reg * 8 + srow) * DH + schunk * 8,
                    (void*)(SM + nxt * 4096 + reg * 512));
        gload_lds16(Vp + (size_t)(reg * 8 + srow) * SEQ + kt + 64 + schunk * 8,
                    (void*)(SM + 8192 + nxt * 4096 + reg * 512));
      }
    }
    const unsigned short* K_ = SM + cur * 4096;
    const unsigned short* V_ = SM + 8192 + cur * 4096;

    // S^T tiles: rows = keys (permuted), cols = q.  s[t][jp][h] elem p holds
    // score(key = jp*32 + quad*8 + h*4 + p  [via row perm], q = wq0+t*16+c)
    f32x4 s[2][2][2] = {};
#pragma unroll
    for (int k2 = 0; k2 < 2; ++k2) {
      s16x8 ak[2][2];
#pragma unroll
      for (int jp = 0; jp < 2; ++jp)
#pragma unroll
        for (int h = 0; h < 2; ++h) {
          int r = jp * 32 + ((c >> 2) << 3) + h * 4 + (c & 3);  // key row perm
          int g = k2 * 4 + quad;
          ak[jp][h] = *(const s16x8*)(K_ + r * 64 + ((g ^ (r & 7)) * 8));
        }
#pragma unroll
      for (int t = 0; t < 2; ++t)
#pragma unroll
        for (int jp = 0; jp < 2; ++jp)
#pragma unroll
          for (int h = 0; h < 2; ++h)
            s[t][jp][h] = __builtin_amdgcn_mfma_f32_16x16x32_bf16(
                ak[jp][h], aq[t][k2], s[t][jp][h], 0, 0, 0);
    }

    // exp2 + lsum + in-register pack to PV B-fragments (k order quad*8+0..7)
    s16x8 bp[2][2];
#pragma unroll
    for (int t = 0; t < 2; ++t)
#pragma unroll
      for (int jp = 0; jp < 2; ++jp) {
        float e00 = fexp2(s[t][jp][0][0]);
        float e01 = fexp2(s[t][jp][0][1]);
        float e02 = fexp2(s[t][jp][0][2]);
        float e03 = fexp2(s[t][jp][0][3]);
        float e10 = fexp2(s[t][jp][1][0]);
        float e11 = fexp2(s[t][jp][1][1]);
        float e12 = fexp2(s[t][jp][1][2]);
        float e13 = fexp2(s[t][jp][1][3]);
        lsum[t] += ((e00 + e01) + (e02 + e03)) + ((e10 + e11) + (e12 + e13));
        union { s16x8 v; unsigned int u[4]; } pk;
        pk.u[0] = pkbf(e00, e01);
        pk.u[1] = pkbf(e02, e03);
        pk.u[2] = pkbf(e10, e11);
        pk.u[3] = pkbf(e12, e13);
        bp[t][jp] = pk.v;
      }

    // O^T += V^T . P^T   (A = V^T rows: lane c = dh row; B = bp)
#pragma unroll
    for (int jp = 0; jp < 2; ++jp)
#pragma unroll
      for (int dt = 0; dt < 4; ++dt) {
        int g = jp * 4 + quad;
        int r = dt * 16 + c;
        s16x8 av = *(const s16x8*)(V_ + r * 64 + ((g ^ (r & 7)) * 8));
#pragma unroll
        for (int t = 0; t < 2; ++t)
          ot[dt][t] = __builtin_amdgcn_mfma_f32_16x16x32_bf16(
              av, bp[t][jp], ot[dt][t], 0, 0, 0);
      }
  }

  // complete row sums across quads (lane bits 4,5)
#pragma unroll
  for (int t = 0; t < 2; ++t) {
    lsum[t] += __shfl_xor(lsum[t], 16);
    lsum[t] += __shfl_xor(lsum[t], 32);
  }

  __syncthreads();   // all tile compute done; reuse SM for O transpose

  // O^T (lane=q col, regs=dh) -> LDS (q rows x dh cols, stride 72) -> global
  unsigned short* Lq = SM + wv_ * (32 * 72);
#pragma unroll
  for (int t = 0; t < 2; ++t) {
    float inv = 1.0f / lsum[t];
#pragma unroll
    for (int dt = 0; dt < 4; ++dt) {
      unsigned int w01 = pkbf(ot[dt][t][0] * inv, ot[dt][t][1] * inv);
      unsigned int w23 = pkbf(ot[dt][t][2] * inv, ot[dt][t][3] * inv);
      unsigned short* p = Lq + (t * 16 + c) * 72 + dt * 16 + quad * 4;
      *(unsigned int*)(p) = w01;
      *(unsigned int*)(p + 2) = w23;
    }
  }
  // wave-local read-back (same wave wrote it; s_waitcnt handles ordering)
  const int b_ = bh >> 4, h_ = bh & 15;
  const int ql = lane >> 1, hf = lane & 1;
  const unsigned short* Lr = Lq + ql * 72 + hf * 32;
  unsigned short* Og = Ob + ((size_t)(b_ * SEQ + wq0 + ql)) * DM + h_ * 64 + hf * 32;
#pragma unroll
  for (int j = 0; j < 4; ++j) {
    s16x8 v = *(const s16x8*)(Lr + j * 8);
    *(s16x8*)(Og + j * 8) = v;
  }
}

// ---------------------------------------------------------------------------
extern "C" void kernel_launch(void* const* d_in, const int* in_sizes, int n_in,
                              void* d_out, int out_size, void* d_ws, size_t ws_size,
                              hipStream_t stream) {
  const float* q  = (const float*)d_in[0];
  const float* kv = (const float*)d_in[1];
  const float* Wq = (const float*)d_in[2];
  const float* bq = (const float*)d_in[3];
  const float* Wk = (const float*)d_in[4];
  const float* bk = (const float*)d_in[5];
  const float* Wv = (const float*)d_in[6];
  const float* bv = (const float*)d_in[7];
  const float* Wo = (const float*)d_in[8];
  const float* bo = (const float*)d_in[9];

  char* ws = (char*)d_ws;
  const size_t MB = 1024 * 1024;
  unsigned short* q_bf  = (unsigned short*)(ws);
  unsigned short* kv_bf = (unsigned short*)(ws + 16 * MB);
  unsigned short* wq_bf = (unsigned short*)(ws + 32 * MB);
  unsigned short* wk_bf = (unsigned short*)(ws + 34 * MB);
  unsigned short* wv_bf = (unsigned short*)(ws + 36 * MB);
  unsigned short* wo_bf = (unsigned short*)(ws + 38 * MB);
  unsigned short* Qb    = (unsigned short*)(ws + 40 * MB);
  unsigned short* Kb    = (unsigned short*)(ws + 56 * MB);
  unsigned short* VTb   = (unsigned short*)(ws + 72 * MB);
  unsigned short* attn  = (unsigned short*)(ws + 88 * MB);

  convert_all<<<2048, 256, 0, stream>>>(q, kv, Wq, Wk, Wv, Wo,
                                        q_bf, kv_bf, wq_bf, wk_bf, wv_bf, wo_bf);
  gemm_qkv8p<<<dim3(32, 12), 512, 0, stream>>>(q_bf, kv_bf, wq_bf, wk_bf, wv_bf,
                                               bq, bk, bv, Qb, Kb, VTb);
  attn_kernel<<<dim3(64, 16), 256, 0, stream>>>(Qb, Kb, VTb, attn);
  gemm_o8p<<<dim3(32, 4), 512, 0, stream>>>(attn, wo_bf, bo, (float*)d_out);
}

// Round 3
// 308.385 us; speedup vs baseline: 1.1020x; 1.1020x over previous
//
#include <hip/hip_runtime.h>

#define NH 16
#define DH 64
#define DM 1024
#define SEQ 2048
#define BATCH 4

typedef short s16x8 __attribute__((ext_vector_type(8)));
typedef float f32x4 __attribute__((ext_vector_type(4)));

__device__ __forceinline__ unsigned short f2bf(float f) {
  union { float f; unsigned int u; } v; v.f = f;
  unsigned int u = v.u;
  unsigned int r = (u + 0x7fffu + ((u >> 16) & 1u)) >> 16;
  return (unsigned short)r;
}

__device__ __forceinline__ unsigned int pkbf(float a, float b) {
#if __has_builtin(__builtin_amdgcn_cvt_pk_bf16_f32)
  typedef short v2s __attribute__((ext_vector_type(2)));
  v2s r = __builtin_amdgcn_cvt_pk_bf16_f32(a, b);
  union { v2s v; unsigned int u; } cv; cv.v = r;
  return cv.u;
#else
  return (unsigned int)f2bf(a) | ((unsigned int)f2bf(b) << 16);
#endif
}

__device__ __forceinline__ float fexp2(float x) {
#if __has_builtin(__builtin_amdgcn_exp2f)
  return __builtin_amdgcn_exp2f(x);
#else
  return exp2f(x);
#endif
}

__device__ __forceinline__ void gload_lds16(const void* g, void* l) {
  __builtin_amdgcn_global_load_lds(
      (const __attribute__((address_space(1))) unsigned int*)g,
      (__attribute__((address_space(3))) unsigned int*)l, 16, 0, 0);
}

// ---------------- fp32 -> bf16 convert (all tensors in one launch) ----------
__global__ void convert_all(const float* __restrict__ q, const float* __restrict__ kv,
                            const float* __restrict__ w0, const float* __restrict__ w1,
                            const float* __restrict__ w2, const float* __restrict__ w3,
                            unsigned short* __restrict__ oq, unsigned short* __restrict__ okv,
                            unsigned short* __restrict__ ow0, unsigned short* __restrict__ ow1,
                            unsigned short* __restrict__ ow2, unsigned short* __restrict__ ow3) {
  const int NQ4 = (BATCH * SEQ * DM) / 4;
  const int NW4 = (DM * DM) / 4;
  const int total = NQ4 * 2 + NW4 * 4;
  for (int i = blockIdx.x * blockDim.x + threadIdx.x; i < total;
       i += gridDim.x * blockDim.x) {
    const float* s; unsigned short* d; int off;
    if (i < NQ4)            { s = q;  d = oq;  off = i; }
    else if (i < 2 * NQ4)   { s = kv; d = okv; off = i - NQ4; }
    else {
      int j = i - 2 * NQ4; int wsel = j / NW4; off = j - wsel * NW4;
      s = (wsel == 0) ? w0 : (wsel == 1) ? w1 : (wsel == 2) ? w2 : w3;
      d = (wsel == 0) ? ow0 : (wsel == 1) ? ow1 : (wsel == 2) ? ow2 : ow3;
    }
    float4 v = *(const float4*)(s + (size_t)off * 4);
    ushort4 o;
    o.x = f2bf(v.x); o.y = f2bf(v.y); o.z = f2bf(v.z); o.w = f2bf(v.w);
    *(ushort4*)(d + (size_t)off * 4) = o;
  }
}

// ---------------- shared GEMM tile body (round-0 verified) ------------------
__device__ __forceinline__ void gemm_tile(const unsigned short* __restrict__ X,
                                          const unsigned short* __restrict__ Wt,
                                          unsigned short* As, unsigned short* Bs,
                                          int m0, int n0, f32x4 (*acc)[4]) {
  const int tid = threadIdx.x;
  const int wv_ = tid >> 6, lane = tid & 63;
  const int quad = lane >> 4, c = lane & 15;
  const int wm = (wv_ >> 1) * 64, wn = (wv_ & 1) * 64;
  const int srow = lane >> 3;
  const int scol = ((lane & 7) ^ srow) * 8;

  for (int kt = 0; kt < DM; kt += 64) {
#pragma unroll
    for (int i = 0; i < 4; ++i) {
      int reg = wv_ * 4 + i;
      gload_lds16(X + (size_t)(m0 + reg * 8 + srow) * DM + kt + scol,
                  (void*)(As + reg * 512));
      gload_lds16(Wt + (size_t)(n0 + reg * 8 + srow) * DM + kt + scol,
                  (void*)(Bs + reg * 512));
    }
    __syncthreads();
#pragma unroll
    for (int k2 = 0; k2 < 2; ++k2) {
      s16x8 a[4], b[4];
      int g = k2 * 4 + quad;
#pragma unroll
      for (int t = 0; t < 4; ++t)
        a[t] = *(const s16x8*)(As + (wm + t * 16 + c) * 64 + ((g ^ (c & 7)) * 8));
#pragma unroll
      for (int t = 0; t < 4; ++t)
        b[t] = *(const s16x8*)(Bs + (wn + t * 16 + c) * 64 + ((g ^ (c & 7)) * 8));
#pragma unroll
      for (int tm = 0; tm < 4; ++tm)
#pragma unroll
        for (int tn = 0; tn < 4; ++tn)
          acc[tm][tn] = __builtin_amdgcn_mfma_f32_16x16x32_bf16(
              a[tm], b[tn], acc[tm][tn], 0, 0, 0);
    }
    __syncthreads();
  }
}

// ---------------- fused QKV projection -------------------------------------
__global__ __launch_bounds__(256)
void gemm_qkv(const unsigned short* __restrict__ Xq,
              const unsigned short* __restrict__ Xkv,
              const unsigned short* __restrict__ W0,
              const unsigned short* __restrict__ W1,
              const unsigned short* __restrict__ W2,
              const float* __restrict__ b0, const float* __restrict__ b1,
              const float* __restrict__ b2,
              unsigned short* __restrict__ OQ, unsigned short* __restrict__ OK_,
              unsigned short* __restrict__ OV) {
  __shared__ alignas(16) unsigned short As[128 * 64];
  __shared__ alignas(16) unsigned short Bs[128 * 64];
  const int m0 = blockIdx.x * 128;
  const int ysel = blockIdx.y >> 3;
  const int n0 = (blockIdx.y & 7) * 128;
  const unsigned short* X = (ysel == 0) ? Xq : Xkv;
  const unsigned short* Wt = (ysel == 0) ? W0 : (ysel == 1) ? W1 : W2;
  const float* bias = (ysel == 0) ? b0 : (ysel == 1) ? b1 : b2;
  unsigned short* Out = (ysel == 0) ? OQ : (ysel == 1) ? OK_ : OV;
  // Q pre-scaled by log2(e)/sqrt(Dh) so attention can use exp2 directly
  const float scale = (ysel == 0) ? 0.1803368801f : 1.0f;

  f32x4 acc[4][4] = {};
  gemm_tile(X, Wt, As, Bs, m0, n0, acc);

  const int tid = threadIdx.x;
  const int wv_ = tid >> 6, lane = tid & 63;
  const int quad = lane >> 4, c = lane & 15;
  const int wm = (wv_ >> 1) * 64, wn = (wv_ & 1) * 64;
#pragma unroll
  for (int tm = 0; tm < 4; ++tm) {
#pragma unroll
    for (int tn = 0; tn < 4; ++tn) {
      int n = n0 + wn + tn * 16 + c;
      float bv = bias[n];
      int m_base = m0 + wm + tm * 16 + quad * 4;
      if (ysel == 2) {
        // V^T: p -> consecutive s; one 8B store
        int b_ = m_base >> 11, s_ = m_base & 2047, h_ = n >> 6, dh = n & 63;
        size_t idx = (((size_t)(b_ * NH + h_)) * DH + dh) * SEQ + s_;
        ushort4 o4;
        o4.x = f2bf(acc[tm][tn][0] + bv);
        o4.y = f2bf(acc[tm][tn][1] + bv);
        o4.z = f2bf(acc[tm][tn][2] + bv);
        o4.w = f2bf(acc[tm][tn][3] + bv);
        *(ushort4*)(&Out[idx]) = o4;
      } else {
#pragma unroll
        for (int p = 0; p < 4; ++p) {
          int m = m_base + p;
          float val = (acc[tm][tn][p] + bv) * scale;
          int b_ = m >> 11, s_ = m & 2047, h_ = n >> 6, dh = n & 63;
          size_t idx = (((size_t)(b_ * NH + h_)) * SEQ + s_) * DH + dh;
          Out[idx] = f2bf(val);
        }
      }
    }
  }
}

// ---------------- output projection (fp32 out) -----------------------------
__global__ __launch_bounds__(256)
void gemm_o(const unsigned short* __restrict__ X,
            const unsigned short* __restrict__ Wt,
            const float* __restrict__ bias, float* __restrict__ Out) {
  __shared__ alignas(16) unsigned short As[128 * 64];
  __shared__ alignas(16) unsigned short Bs[128 * 64];
  const int m0 = blockIdx.x * 128;
  const int n0 = blockIdx.y * 128;
  f32x4 acc[4][4] = {};
  gemm_tile(X, Wt, As, Bs, m0, n0, acc);

  const int tid = threadIdx.x;
  const int wv_ = tid >> 6, lane = tid & 63;
  const int quad = lane >> 4, c = lane & 15;
  const int wm = (wv_ >> 1) * 64, wn = (wv_ & 1) * 64;
#pragma unroll
  for (int tm = 0; tm < 4; ++tm) {
#pragma unroll
    for (int tn = 0; tn < 4; ++tn) {
      int n = n0 + wn + tn * 16 + c;
      float bv = bias[n];
#pragma unroll
      for (int p = 0; p < 4; ++p) {
        int m = m0 + wm + tm * 16 + quad * 4 + p;
        Out[(size_t)m * DM + n] = acc[tm][tn][p] + bv;
      }
    }
  }
}

// ---------------- flash attention v5: QBLK=64 per wave ---------------------
// Same math/layout as v4 but each wave owns 64 q-rows (4 x 16 q-tiles), so
// the per-tile K/V LDS fragment reads (which are q-independent) are amortized
// over 2x the MFMA work -> LDS pipe per FLOP halves. Grid y: 16 -> 8.
// O-writeout runs in two wave-local half-passes to keep LDS at 32 KB.
__global__ __launch_bounds__(256, 2)
void attn_kernel(const unsigned short* __restrict__ Qb,
                 const unsigned short* __restrict__ Kb,
                 const unsigned short* __restrict__ VTb,
                 unsigned short* __restrict__ Ob) {
  __shared__ alignas(16) unsigned short SM[16384];   // 32 KB

  const int tid = threadIdx.x, wv_ = tid >> 6, lane = tid & 63;
  const int quad = lane >> 4, c = lane & 15;
  const int bh = blockIdx.x, qb = blockIdx.y;
  const unsigned short* Qp = Qb + (size_t)bh * SEQ * DH;
  const unsigned short* Kp = Kb + (size_t)bh * SEQ * DH;
  const unsigned short* Vp = VTb + (size_t)bh * DH * SEQ;
  const int wq0 = qb * 256 + wv_ * 64;

  // Q fragments (B-operand: lane c = q column) live in registers
  s16x8 aq[4][2];
#pragma unroll
  for (int t = 0; t < 4; ++t)
#pragma unroll
    for (int k2 = 0; k2 < 2; ++k2)
      aq[t][k2] = *(const s16x8*)(Qp + (size_t)(wq0 + t * 16 + c) * DH +
                                  k2 * 32 + quad * 8);

  f32x4 ot[4][4] = {};     // O^T accum: [dh-tile][q-tile], lane c = q col
  float lsum[4] = {};      // per-lane partial row sums (this quad's keys)

  const int srow = lane >> 3;
  const int schunk = (lane & 7) ^ srow;

  // prologue: stage tile 0 -> buffer 0  (K at SM+0/SM+4096, V at +8192/+12288)
#pragma unroll
  for (int i = 0; i < 2; ++i) {
    int reg = wv_ * 2 + i;
    gload_lds16(Kp + (size_t)(reg * 8 + srow) * DH + schunk * 8,
                (void*)(SM + reg * 512));
    gload_lds16(Vp + (size_t)(reg * 8 + srow) * SEQ + schunk * 8,
                (void*)(SM + 8192 + reg * 512));
  }

  for (int kt = 0; kt < SEQ; kt += 64) {
    const int cur = (kt >> 6) & 1;
    __syncthreads();   // drains this tile's loads; frees other buffer
    if (kt + 64 < SEQ) {
      const int nxt = cur ^ 1;
#pragma unroll
      for (int i = 0; i < 2; ++i) {
        int reg = wv_ * 2 + i;
        gload_lds16(Kp + (size_t)(kt + 64 + reg * 8 + srow) * DH + schunk * 8,
                    (void*)(SM + nxt * 4096 + reg * 512));
        gload_lds16(Vp + (size_t)(reg * 8 + srow) * SEQ + kt + 64 + schunk * 8,
                    (void*)(SM + 8192 + nxt * 4096 + reg * 512));
      }
    }
    const unsigned short* K_ = SM + cur * 4096;
    const unsigned short* V_ = SM + 8192 + cur * 4096;

    // S^T tiles: rows = keys (permuted), cols = q.  s[t][jp][h] elem p holds
    // score(key = jp*32 + quad*8 + h*4 + p  [via row perm], q = wq0+t*16+c)
    f32x4 s[4][2][2] = {};
#pragma unroll
    for (int k2 = 0; k2 < 2; ++k2) {
      s16x8 ak[2][2];
#pragma unroll
      for (int jp = 0; jp < 2; ++jp)
#pragma unroll
        for (int h = 0; h < 2; ++h) {
          int r = jp * 32 + ((c >> 2) << 3) + h * 4 + (c & 3);  // key row perm
          int g = k2 * 4 + quad;
          ak[jp][h] = *(const s16x8*)(K_ + r * 64 + ((g ^ (r & 7)) * 8));
        }
#pragma unroll
      for (int t = 0; t < 4; ++t)
#pragma unroll
        for (int jp = 0; jp < 2; ++jp)
#pragma unroll
          for (int h = 0; h < 2; ++h)
            s[t][jp][h] = __builtin_amdgcn_mfma_f32_16x16x32_bf16(
                ak[jp][h], aq[t][k2], s[t][jp][h], 0, 0, 0);
    }

    // exp2 + lsum + in-register pack to PV B-fragments (k order quad*8+0..7)
    s16x8 bp[4][2];
#pragma unroll
    for (int t = 0; t < 4; ++t)
#pragma unroll
      for (int jp = 0; jp < 2; ++jp) {
        float e00 = fexp2(s[t][jp][0][0]);
        float e01 = fexp2(s[t][jp][0][1]);
        float e02 = fexp2(s[t][jp][0][2]);
        float e03 = fexp2(s[t][jp][0][3]);
        float e10 = fexp2(s[t][jp][1][0]);
        float e11 = fexp2(s[t][jp][1][1]);
        float e12 = fexp2(s[t][jp][1][2]);
        float e13 = fexp2(s[t][jp][1][3]);
        lsum[t] += ((e00 + e01) + (e02 + e03)) + ((e10 + e11) + (e12 + e13));
        union { s16x8 v; unsigned int u[4]; } pk;
        pk.u[0] = pkbf(e00, e01);
        pk.u[1] = pkbf(e02, e03);
        pk.u[2] = pkbf(e10, e11);
        pk.u[3] = pkbf(e12, e13);
        bp[t][jp] = pk.v;
      }

    // O^T += V^T . P^T   (A = V^T rows: lane c = dh row; B = bp)
#pragma unroll
    for (int jp = 0; jp < 2; ++jp)
#pragma unroll
      for (int dt = 0; dt < 4; ++dt) {
        int g = jp * 4 + quad;
        int r = dt * 16 + c;
        s16x8 av = *(const s16x8*)(V_ + r * 64 + ((g ^ (r & 7)) * 8));
#pragma unroll
        for (int t = 0; t < 4; ++t)
          ot[dt][t] = __builtin_amdgcn_mfma_f32_16x16x32_bf16(
              av, bp[t][jp], ot[dt][t], 0, 0, 0);
      }
  }

  // complete row sums across quads (lane bits 4,5)
#pragma unroll
  for (int t = 0; t < 4; ++t) {
    lsum[t] += __shfl_xor(lsum[t], 16);
    lsum[t] += __shfl_xor(lsum[t], 32);
  }

  __syncthreads();   // all tile compute done; reuse SM for O transpose

  // O^T (lane=q col, regs=dh) -> LDS (q rows x dh cols, stride 72) -> global,
  // in two wave-local half-passes (q rows wq0+half*32 .. +31).
  const int b_ = bh >> 4, h_ = bh & 15;
  const int ql = lane >> 1, hf = lane & 1;
  unsigned short* Lq = SM + wv_ * (32 * 72);
#pragma unroll
  for (int half = 0; half < 2; ++half) {
    if (half) asm volatile("s_waitcnt lgkmcnt(0)" ::: "memory");  // pass-0 reads done
#pragma unroll
    for (int t2 = 0; t2 < 2; ++t2) {
      int t = half * 2 + t2;
      float inv = 1.0f / lsum[t];
#pragma unroll
      for (int dt = 0; dt < 4; ++dt) {
        unsigned int w01 = pkbf(ot[dt][t][0] * inv, ot[dt][t][1] * inv);
        unsigned int w23 = pkbf(ot[dt][t][2] * inv, ot[dt][t][3] * inv);
        unsigned short* p = Lq + (t2 * 16 + c) * 72 + dt * 16 + quad * 4;
        *(unsigned int*)(p) = w01;
        *(unsigned int*)(p + 2) = w23;
      }
    }
    // wave-local read-back (same wave wrote it; s_waitcnt handles ordering)
    const unsigned short* Lr = Lq + ql * 72 + hf * 32;
    unsigned short* Og = Ob + ((size_t)(b_ * SEQ + wq0 + half * 32 + ql)) * DM +
                         h_ * 64 + hf * 32;
#pragma unroll
    for (int j = 0; j < 4; ++j) {
      s16x8 v = *(const s16x8*)(Lr + j * 8);
      *(s16x8*)(Og + j * 8) = v;
    }
  }
}

// ---------------------------------------------------------------------------
extern "C" void kernel_launch(void* const* d_in, const int* in_sizes, int n_in,
                              void* d_out, int out_size, void* d_ws, size_t ws_size,
                              hipStream_t stream) {
  const float* q  = (const float*)d_in[0];
  const float* kv = (const float*)d_in[1];
  const float* Wq = (const float*)d_in[2];
  const float* bq = (const float*)d_in[3];
  const float* Wk = (const float*)d_in[4];
  const float* bk = (const float*)d_in[5];
  const float* Wv = (const float*)d_in[6];
  const float* bv = (const float*)d_in[7];
  const float* Wo = (const float*)d_in[8];
  const float* bo = (const float*)d_in[9];

  char* ws = (char*)d_ws;
  const size_t MB = 1024 * 1024;
  unsigned short* q_bf  = (unsigned short*)(ws);
  unsigned short* kv_bf = (unsigned short*)(ws + 16 * MB);
  unsigned short* wq_bf = (unsigned short*)(ws + 32 * MB);
  unsigned short* wk_bf = (unsigned short*)(ws + 34 * MB);
  unsigned short* wv_bf = (unsigned short*)(ws + 36 * MB);
  unsigned short* wo_bf = (unsigned short*)(ws + 38 * MB);
  unsigned short* Qb    = (unsigned short*)(ws + 40 * MB);
  unsigned short* Kb    = (unsigned short*)(ws + 56 * MB);
  unsigned short* VTb   = (unsigned short*)(ws + 72 * MB);
  unsigned short* attn  = (unsigned short*)(ws + 88 * MB);

  convert_all<<<2048, 256, 0, stream>>>(q, kv, Wq, Wk, Wv, Wo,
                                        q_bf, kv_bf, wq_bf, wk_bf, wv_bf, wo_bf);
  gemm_qkv<<<dim3(64, 24), 256, 0, stream>>>(q_bf, kv_bf, wq_bf, wk_bf, wv_bf,
                                             bq, bk, bv, Qb, Kb, VTb);
  attn_kernel<<<dim3(64, 8), 256, 0, stream>>>(Qb, Kb, VTb, attn);
  gemm_o<<<dim3(64, 8), 256, 0, stream>>>(attn, wo_bf, bo, (float*)d_out);
}